// Round 1
// baseline (193.134 us; speedup 1.0000x reference)
//
#include <hip/hip_runtime.h>
#include <math.h>

#define NROWS 32768
#define NDIM 64
#define NCODE 1024
#define BN 64
#define BK 128
#define TM 4
#define TN 8
#define XPAD 68          // +4 pad: 16B-aligned rows, bank spread
#define AMB_CAP 8192
#define GAP_THRESH 1e-3f // fp32-vs-fp64 dist noise ~1e-5; 100x margin

// order-preserving float->uint key (monotone for all floats)
__device__ __forceinline__ unsigned okey(float f) {
    unsigned u = __float_as_uint(f);
    return (u >> 31) ? ~u : (u | 0x80000000u);
}

__global__ __launch_bounds__(256) void vq_init(
    const float* __restrict__ cb, float* __restrict__ cnorm,
    unsigned* __restrict__ minK, unsigned* __restrict__ counter,
    float* __restrict__ gsumsq)
{
    int k = blockIdx.x * 256 + threadIdx.x;
    if (k < NCODE) {
        const float* cr = cb + (size_t)k * NDIM;
        float s = 0.f;
        #pragma unroll
        for (int d = 0; d < NDIM; d += 4) {
            float4 v = *(const float4*)(cr + d);
            s += v.x*v.x + v.y*v.y + v.z*v.z + v.w*v.w;
        }
        cnorm[k] = s;
        minK[k] = 0xFF800000u;  // okey(+inf)
    }
    if (k == 0) { *counter = 0u; *gsumsq = 0.f; }
}

__global__ __launch_bounds__(256) void vq_main(
    const float* __restrict__ x, const float* __restrict__ cb,
    float* __restrict__ out, const float* __restrict__ cnorm,
    unsigned* __restrict__ minK, unsigned* __restrict__ counter,
    int* __restrict__ amb, float* __restrict__ gsumsq)
{
    __shared__ float xs[BN * XPAD];      // 17408 B
    __shared__ float cs[BK * XPAD];      // 34816 B
    __shared__ float scr[3072];          // union: codemin[128][17] | top2 d1/k1/d2 [64][16]
    __shared__ float xnormS[BN];
    __shared__ int   tokenS[BN];
    __shared__ float redS[4];

    const int tid = threadIdx.x;
    const int tx = tid & 15;             // code dimension
    const int ty = tid >> 4;             // row dimension
    const int n0 = blockIdx.x * BN;

    // ---- stage x tile (contiguous 16 KB) ----
    const float* xg = x + (size_t)n0 * NDIM;
    #pragma unroll
    for (int i = 0; i < 4; i++) {
        int flat = (i * 256 + tid) * 4;
        float4 v = *(const float4*)(xg + flat);
        int r = flat >> 6, c = flat & 63;
        *(float4*)&xs[r * XPAD + c] = v;
    }
    __syncthreads();
    if (tid < BN) {
        float s = 0.f;
        #pragma unroll
        for (int d = 0; d < NDIM; d += 4) {
            float4 v = *(const float4*)&xs[tid * XPAD + d];
            s += v.x*v.x + v.y*v.y + v.z*v.z + v.w*v.w;
        }
        xnormS[tid] = s;
    }

    float d1[TM], d2[TM];
    int   k1[TM];
    #pragma unroll
    for (int r = 0; r < TM; r++) { d1[r] = INFINITY; d2[r] = INFINITY; k1[r] = 0; }

    for (int ck = 0; ck < NCODE / BK; ck++) {
        __syncthreads();   // prior chunk done with cs & scr
        const float* cg = cb + (size_t)ck * BK * NDIM;
        #pragma unroll
        for (int i = 0; i < 8; i++) {
            int flat = (i * 256 + tid) * 4;
            float4 v = *(const float4*)(cg + flat);
            int r = flat >> 6, c = flat & 63;
            *(float4*)&cs[r * XPAD + c] = v;
        }
        __syncthreads();

        float s[TM][TN];
        #pragma unroll
        for (int r = 0; r < TM; r++)
            #pragma unroll
            for (int j = 0; j < TN; j++) s[r][j] = 0.f;

        // thread's codes: k = ck*BK + j*16 + tx  (stride-16 => LDS bank stride tx*4: 2-way only)
        const float* xbase = &xs[(ty * TM) * XPAD];
        const float* cbase = &cs[tx * XPAD];
        #pragma unroll 4
        for (int d = 0; d < NDIM; d += 4) {
            float4 xv[TM], cv[TN];
            #pragma unroll
            for (int r = 0; r < TM; r++) xv[r] = *(const float4*)&xbase[r * XPAD + d];
            #pragma unroll
            for (int j = 0; j < TN; j++) cv[j] = *(const float4*)&cbase[(j * 16) * XPAD + d];
            #pragma unroll
            for (int r = 0; r < TM; r++)
                #pragma unroll
                for (int j = 0; j < TN; j++) {
                    s[r][j] = fmaf(xv[r].x, cv[j].x, s[r][j]);
                    s[r][j] = fmaf(xv[r].y, cv[j].y, s[r][j]);
                    s[r][j] = fmaf(xv[r].z, cv[j].z, s[r][j]);
                    s[r][j] = fmaf(xv[r].w, cv[j].w, s[r][j]);
                }
        }

        // ---- epilogue: dist, top-2 per row, per-code min over rows ----
        float cn[TN], cmin[TN];
        #pragma unroll
        for (int j = 0; j < TN; j++) {
            cn[j] = cnorm[ck * BK + j * 16 + tx];
            cmin[j] = INFINITY;
        }
        #pragma unroll
        for (int r = 0; r < TM; r++) {
            float xn = xnormS[ty * TM + r];
            #pragma unroll
            for (int j = 0; j < TN; j++) {
                float dist = (xn - 2.f * s[r][j]) + cn[j];  // matches ref assoc order
                int k = ck * BK + j * 16 + tx;
                if (dist < d1[r]) { d2[r] = d1[r]; d1[r] = dist; k1[r] = k; }
                else if (dist < d2[r]) d2[r] = dist;
                cmin[j] = fminf(cmin[j], dist);
            }
        }
        #pragma unroll
        for (int j = 0; j < TN; j++) scr[(j * 16 + tx) * 17 + ty] = cmin[j];
        __syncthreads();
        if (tid < BK) {
            float m = scr[tid * 17];
            #pragma unroll
            for (int i = 1; i < 16; i++) m = fminf(m, scr[tid * 17 + i]);
            unsigned key = okey(m);
            unsigned cur = minK[ck * BK + tid];   // cheap filter; races benign (monotone)
            if (key < cur) atomicMin(&minK[ck * BK + tid], key);
        }
    }
    __syncthreads();

    // ---- merge top-2 across the 16 tx threads per row ----
    int* scri = (int*)scr;
    #pragma unroll
    for (int r = 0; r < TM; r++) {
        int row = ty * TM + r;
        scr [row * 16 + tx] = d1[r];
        scri[1024 + row * 16 + tx] = k1[r];
        scr [2048 + row * 16 + tx] = d2[r];
    }
    __syncthreads();
    if (tid < BN) {
        float D1 = INFINITY, D2 = INFINITY; int K1 = 0;
        #pragma unroll
        for (int t = 0; t < 16; t++) {
            float a1 = scr[tid * 16 + t];
            int   ak = scri[1024 + tid * 16 + t];
            float a2 = scr[2048 + tid * 16 + t];
            if (a1 < D1 || (a1 == D1 && ak < K1)) { D2 = fminf(D1, a2); D1 = a1; K1 = ak; }
            else D2 = fminf(D2, a1);
        }
        tokenS[tid] = K1;
        if (D2 - D1 < GAP_THRESH) {           // ambiguous under fp32 noise -> fp64 fixup
            unsigned idx = atomicAdd(counter, 1u);
            if (idx < AMB_CAP) { amb[2 * idx] = n0 + tid; amb[2 * idx + 1] = K1; }
        }
    }
    __syncthreads();

    // ---- emb gather + write + sumsq partial ----
    float acc = 0.f;
    float* og = out + (size_t)n0 * NDIM;
    for (int e = tid; e < BN * NDIM; e += 256) {
        int r = e >> 6, d = e & 63;
        float cv = cb[(size_t)tokenS[r] * NDIM + d];
        float xv = xs[r * XPAD + d];
        og[e] = cv;
        float df = cv - xv;
        acc = fmaf(df, df, acc);
    }
    #pragma unroll
    for (int o = 32; o > 0; o >>= 1) acc += __shfl_down(acc, o);
    if ((tid & 63) == 0) redS[tid >> 6] = acc;
    __syncthreads();
    if (tid == 0) atomicAdd(gsumsq, redS[0] + redS[1] + redS[2] + redS[3]);
}

// fp64 re-decision for rows whose fp32 top-2 gap was below threshold.
// One wave per row; lane L owns codes {j*64+L}.
__global__ __launch_bounds__(256) void vq_fixup(
    const float* __restrict__ x, const float* __restrict__ cb,
    float* __restrict__ out, const unsigned* __restrict__ counter,
    const int* __restrict__ amb, float* __restrict__ gsumsq)
{
    int lane = threadIdx.x & 63;
    int gw = (blockIdx.x * 256 + threadIdx.x) >> 6;   // 256 waves total
    unsigned cnt = *counter;
    if (cnt > AMB_CAP) cnt = AMB_CAP;
    for (unsigned i = gw; i < cnt; i += 256) {
        int row  = amb[2 * i];
        int oldk = amb[2 * i + 1];
        float xf = x[(size_t)row * NDIM + lane];
        double xd = (double)xf;
        double xn = xd * xd;
        #pragma unroll
        for (int o = 1; o < 64; o <<= 1) xn += __shfl_xor(xn, o);
        double bd = INFINITY; int bk = 0;
        for (int j = 0; j < 16; j++) {
            int k = j * 64 + lane;
            const float* cr = cb + (size_t)k * NDIM;
            double dot = 0.0, cn2 = 0.0;
            for (int d = 0; d < NDIM; d++) {
                double cv = (double)cr[d];
                double xv = (double)__shfl(xf, d);
                dot += xv * cv;
                cn2 += cv * cv;
            }
            double dist = (xn - 2.0 * dot) + cn2;
            if (dist < bd) { bd = dist; bk = k; }   // k ascending within lane
        }
        #pragma unroll
        for (int o = 1; o < 64; o <<= 1) {          // argmin w/ first-index tiebreak
            double od = __shfl_xor(bd, o);
            int    ok = __shfl_xor(bk, o);
            if (od < bd || (od == bd && ok < bk)) { bd = od; bk = ok; }
        }
        if (bk != oldk) {
            float cnew = cb[(size_t)bk * NDIM + lane];
            float cold = cb[(size_t)oldk * NDIM + lane];
            out[(size_t)row * NDIM + lane] = cnew;
            double dn = (double)cnew - xd;
            double dl = (double)cold - xd;
            double delta = dn * dn - dl * dl;
            #pragma unroll
            for (int o = 1; o < 64; o <<= 1) delta += __shfl_xor(delta, o);
            if (lane == 0) atomicAdd(gsumsq, (float)delta);
        }
    }
}

__global__ __launch_bounds__(256) void vq_finalize(
    const unsigned* __restrict__ minK, const float* __restrict__ gsumsq,
    float* __restrict__ out_loss)
{
    __shared__ float redS[4];
    float s = 0.f;
    for (int k = threadIdx.x; k < NCODE; k += 256) {
        unsigned u = minK[k];
        unsigned b = (u & 0x80000000u) ? (u ^ 0x80000000u) : ~u;  // decode okey
        s += __uint_as_float(b);
    }
    #pragma unroll
    for (int o = 32; o > 0; o >>= 1) s += __shfl_down(s, o);
    if ((threadIdx.x & 63) == 0) redS[threadIdx.x >> 6] = s;
    __syncthreads();
    if (threadIdx.x == 0) {
        float tot = redS[0] + redS[1] + redS[2] + redS[3];
        float loss = 1.25f * (*gsumsq / 2097152.0f) + 0.1f * (tot / 1024.0f);
        out_loss[0] = loss;
    }
}

extern "C" void kernel_launch(void* const* d_in, const int* in_sizes, int n_in,
                              void* d_out, int out_size, void* d_ws, size_t ws_size,
                              hipStream_t stream) {
    const float* x  = (const float*)d_in[0];   // [32768, 64]
    const float* cb = (const float*)d_in[1];   // [1024, 64]
    float* out = (float*)d_out;                // [0,2097152): emb; [2097152]: loss

    char* ws = (char*)d_ws;
    unsigned* counter = (unsigned*)ws;                 // 4 B
    float*    gsumsq  = (float*)(ws + 4);              // 4 B
    float*    cnorm   = (float*)(ws + 16);             // 4 KB
    unsigned* minK    = (unsigned*)(ws + 16 + 4096);   // 4 KB
    int*      amb     = (int*)(ws + 16 + 8192);        // 64 KB

    vq_init    <<<4,   256, 0, stream>>>(cb, cnorm, minK, counter, gsumsq);
    vq_main    <<<NROWS / BN, 256, 0, stream>>>(x, cb, out, cnorm, minK, counter, amb, gsumsq);
    vq_fixup   <<<64,  256, 0, stream>>>(x, cb, out, counter, amb, gsumsq);
    vq_finalize<<<1,   256, 0, stream>>>(minK, gsumsq, out + 2097152);
}